// Round 13
// baseline (3183.387 us; speedup 1.0000x reference)
//
#include <hip/hip_runtime.h>
#include <hip/hip_bf16.h>

typedef __bf16  bf16_8 __attribute__((ext_vector_type(8)));
typedef short   s16_8  __attribute__((ext_vector_type(8)));
typedef float   f32_4  __attribute__((ext_vector_type(4)));

#define T_ 512

// Issue 8 global_load_dwordx4 (one mt group: frag i=0..7, stride 1024B) from
// base b0 (i=0..3) and b0+4096 (i=4..7). No wait — caller waits via VMWAIT.
// Early-clobber outputs: must not alias the base-address registers.
#define LD8(d0,d1,d2,d3,d4,d5,d6,d7, BASE)                                  \
  { unsigned long long _b0 = (BASE), _b1 = (BASE) + 4096ull;                \
    asm volatile(                                                           \
      "global_load_dwordx4 %0, %8, off\n\t"                                 \
      "global_load_dwordx4 %1, %8, off offset:1024\n\t"                     \
      "global_load_dwordx4 %2, %8, off offset:2048\n\t"                     \
      "global_load_dwordx4 %3, %8, off offset:3072\n\t"                     \
      "global_load_dwordx4 %4, %9, off\n\t"                                 \
      "global_load_dwordx4 %5, %9, off offset:1024\n\t"                     \
      "global_load_dwordx4 %6, %9, off offset:2048\n\t"                     \
      "global_load_dwordx4 %7, %9, off offset:3072\n\t"                     \
      : "=&v"(d0),"=&v"(d1),"=&v"(d2),"=&v"(d3),                            \
        "=&v"(d4),"=&v"(d5),"=&v"(d6),"=&v"(d7)                             \
      : "v"(_b0), "v"(_b1)); }

// Coherent variant for h: sc0 sc1 = bypass L1/L2, read at LLC (the coherence
// point where the sc1 publishes land). Fenceless coherence (r11-proven).
#define LD8C(d0,d1,d2,d3,d4,d5,d6,d7, BASE)                                 \
  { unsigned long long _b0 = (BASE), _b1 = (BASE) + 4096ull;                \
    asm volatile(                                                           \
      "global_load_dwordx4 %0, %8, off sc0 sc1\n\t"                         \
      "global_load_dwordx4 %1, %8, off offset:1024 sc0 sc1\n\t"             \
      "global_load_dwordx4 %2, %8, off offset:2048 sc0 sc1\n\t"             \
      "global_load_dwordx4 %3, %8, off offset:3072 sc0 sc1\n\t"             \
      "global_load_dwordx4 %4, %9, off sc0 sc1\n\t"                         \
      "global_load_dwordx4 %5, %9, off offset:1024 sc0 sc1\n\t"             \
      "global_load_dwordx4 %6, %9, off offset:2048 sc0 sc1\n\t"             \
      "global_load_dwordx4 %7, %9, off offset:3072 sc0 sc1\n\t"             \
      : "=&v"(d0),"=&v"(d1),"=&v"(d2),"=&v"(d3),                            \
        "=&v"(d4),"=&v"(d5),"=&v"(d6),"=&v"(d7)                             \
      : "v"(_b0), "v"(_b1)); }

#define LD32(AF, BASE)                                                      \
  LD8(AF[0][0],AF[0][1],AF[0][2],AF[0][3],AF[0][4],AF[0][5],AF[0][6],AF[0][7], (BASE));          \
  LD8(AF[1][0],AF[1][1],AF[1][2],AF[1][3],AF[1][4],AF[1][5],AF[1][6],AF[1][7], (BASE)+32768ull); \
  LD8(AF[2][0],AF[2][1],AF[2][2],AF[2][3],AF[2][4],AF[2][5],AF[2][6],AF[2][7], (BASE)+65536ull); \
  LD8(AF[3][0],AF[3][1],AF[3][2],AF[3][3],AF[3][4],AF[3][5],AF[3][6],AF[3][7], (BASE)+98304ull);

#define LD32C(AF, BASE)                                                     \
  LD8C(AF[0][0],AF[0][1],AF[0][2],AF[0][3],AF[0][4],AF[0][5],AF[0][6],AF[0][7], (BASE));          \
  LD8C(AF[1][0],AF[1][1],AF[1][2],AF[1][3],AF[1][4],AF[1][5],AF[1][6],AF[1][7], (BASE)+32768ull); \
  LD8C(AF[2][0],AF[2][1],AF[2][2],AF[2][3],AF[2][4],AF[2][5],AF[2][6],AF[2][7], (BASE)+65536ull); \
  LD8C(AF[3][0],AF[3][1],AF[3][2],AF[3][3],AF[3][4],AF[3][5],AF[3][6],AF[3][7], (BASE)+98304ull);

// Wait for all loads, then fence the scheduler so no af-consumer (MFMA is
// register-only, NOT ordered by the "memory" clobber) hoists above it.
#define VMWAIT_FENCE                                                        \
  asm volatile("s_waitcnt vmcnt(0)" ::: "memory");                          \
  __builtin_amdgcn_sched_barrier(0)

// ---------------- P1: X fp32 [T][B][1024] -> xfrag bf16 [T][4 mt][32 kc][64 lane][8]
__global__ __launch_bounds__(256) void p1_xfrag(const float* __restrict__ X,
                                                bf16_8* __restrict__ xf) {
  size_t n = (size_t)blockIdx.x * 256 + threadIdx.x;   // 4,194,304 total
  int lane = (int)(n & 63);
  int kc   = (int)((n >> 6) & 31);
  int mt   = (int)((n >> 11) & 3);
  int t    = (int)(n >> 13);
  int b  = 16 * mt + (lane & 15);
  int i0 = 32 * kc + (lane >> 4) * 8;
  const float4* ps = (const float4*)(X + ((size_t)t * 64 + b) * 1024 + i0);
  float4 a = ps[0], c = ps[1];
  bf16_8 v;
  v[0]=(__bf16)a.x; v[1]=(__bf16)a.y; v[2]=(__bf16)a.z; v[3]=(__bf16)a.w;
  v[4]=(__bf16)c.x; v[5]=(__bf16)c.y; v[6]=(__bf16)c.z; v[7]=(__bf16)c.w;
  xf[n] = v;
}

// ---------------- P2: Wi,Wh fp32 -> wfrag bf16 [256 cu][64 kc][64 lane][8]
__global__ __launch_bounds__(256) void p2_wfrag(const float* __restrict__ Wi,
                                                const float* __restrict__ Wh,
                                                bf16_8* __restrict__ wf) {
  size_t n = (size_t)blockIdx.x * 256 + threadIdx.x;   // 1,048,576 total
  int lane = (int)(n & 63);
  int kc   = (int)((n >> 6) & 63);
  int cu   = (int)(n >> 12);
  int n16 = lane & 15;
  int g  = n16 >> 2;
  int jj = n16 & 3;
  int col = 4 * cu + jj;
  int k = 32 * kc + (lane >> 4) * 8;
  const float* src = (k < 1024)
      ? (Wi + ((size_t)g * 1024 + col) * 1024 + k)
      : (Wh + ((size_t)g * 1024 + col) * 1024 + (k - 1024));
  const float4* ps = (const float4*)src;
  float4 a = ps[0], c = ps[1];
  bf16_8 v;
  v[0]=(__bf16)a.x; v[1]=(__bf16)a.y; v[2]=(__bf16)a.z; v[3]=(__bf16)a.w;
  v[4]=(__bf16)c.x; v[5]=(__bf16)c.y; v[6]=(__bf16)c.z; v[7]=(__bf16)c.w;
  wf[n] = v;
}

// ---------------- persistent LSTM: 256 blocks x 512 threads (8 waves)
// DATAFLOW SYNC (no global barrier): h-wave wv consumes h-columns published
// by producer groups 2(wv&3), 2(wv&3)+1 only -> it polls exactly those 2
// group counters. A block's 4 h-waves cover all 8 groups, so block-level
// skew stays <=1 and the double-buffered h remains race-free.
// Phase A: h-waves {poll 2 groups -> LLC-direct h-load -> MFMA}.
// Phase B: elementwise on h-waves.
// Phase C: x-waves x-GEMM(t+1); wave4 publish h (sc1) -> ack -> arrive RMW.
__global__ __launch_bounds__(512, 2) void lstm_persist(
    const float* __restrict__ bi, const float* __restrict__ bh,
    const s16_8* __restrict__ xfrag, const s16_8* __restrict__ wfrag,
    s16_8* __restrict__ hfrag, float* __restrict__ out,
    unsigned int* __restrict__ ctr)
{
  __shared__ float gx[2][4][64][17];   // x-partials, double-buffered  34,816 B
  __shared__ float gh[4][64][17];      // h-partials                   17,408 B
  __shared__ float hvals[4][64];       // h gather for pack             1,024 B

  const int tid  = threadIdx.x;
  const int cu   = blockIdx.x;
  const int wv   = tid >> 6;
  const int lane = tid & 63;
  const bool ish = (wv >= 4);
  const unsigned long long lofs = (unsigned long long)(((wv & 3) * 8) * 1024 + lane * 16);

  // resident B-fragments of W (registers): 16 rows (4 cols x 4 gates) per CU
  s16_8 wf[8];
#pragma unroll
  for (int i = 0; i < 8; ++i)
    wf[i] = wfrag[((size_t)cu * 64 + wv * 8 + i) * 64 + lane];
#pragma unroll
  for (int i = 0; i < 8; ++i)
    asm volatile("" : "+v"(wf[i]));    // pin resident: no remat/re-load per step

  // elementwise identity (threads 256..511): eb = batch, ejj = column-in-block
  const int et  = tid - 256;
  const int eb  = et & 63;
  const int ejj = (et >> 6) & 3;
  const int j   = cu * 4 + ejj;
  float bias4[4] = {0.f, 0.f, 0.f, 0.f};
  if (tid >= 256) {
#pragma unroll
    for (int g = 0; g < 4; ++g) bias4[g] = bi[g * 1024 + j] + bh[g * 1024 + j];
  }
  float cst = 0.f, hval = 0.f;

  unsigned int* grp = ctr + (cu >> 5) * 64;   // 8 group counters, 256 B apart

  // ---- prologue: x-waves compute gx(0)
  if (!ish) {
    s16_8 af[4][8];
    LD32(af, (unsigned long long)(const char*)xfrag + lofs);
    VMWAIT_FENCE;
    f32_4 acc[4];
#pragma unroll
    for (int mt = 0; mt < 4; ++mt) { f32_4 z = {0.f,0.f,0.f,0.f}; acc[mt] = z; }
#pragma unroll
    for (int i = 0; i < 8; ++i)
#pragma unroll
      for (int mt = 0; mt < 4; ++mt)
        acc[mt] = __builtin_amdgcn_mfma_f32_16x16x32_bf16(af[mt][i], wf[i], acc[mt], 0, 0, 0);
#pragma unroll
    for (int mt = 0; mt < 4; ++mt)
#pragma unroll
      for (int r = 0; r < 4; ++r)
        gx[0][wv][mt * 16 + (lane >> 4) * 4 + r][lane & 15] = acc[mt][r];
  }
  __syncthreads();

  for (int t = 0; t < T_; ++t) {
    // ---- phase A: h-waves dataflow-wait on their 2 producer groups, then
    //      LLC-direct h-load + MFMA; x-waves x-GEMM(t+1) (no wait needed).
    if (ish) {
      const unsigned tgt = 32u * (unsigned)t;   // groups published h(t-1)
      if (lane < 2) {
        unsigned int* cc = ctr + ((wv & 3) * 2 + lane) * 64;
        while (__hip_atomic_load(cc, __ATOMIC_RELAXED, __HIP_MEMORY_SCOPE_AGENT) < tgt)
          __builtin_amdgcn_s_sleep(1);
      }
      __builtin_amdgcn_sched_barrier(0);        // loads may not hoist above poll
      s16_8 af[4][8];
      LD32C(af, (unsigned long long)((const char*)hfrag + (size_t)(t & 1) * 131072) + lofs);
      VMWAIT_FENCE;
      f32_4 acc[4];
#pragma unroll
      for (int mt = 0; mt < 4; ++mt) { f32_4 z = {0.f,0.f,0.f,0.f}; acc[mt] = z; }
#pragma unroll
      for (int i = 0; i < 8; ++i)
#pragma unroll
        for (int mt = 0; mt < 4; ++mt)
          acc[mt] = __builtin_amdgcn_mfma_f32_16x16x32_bf16(af[mt][i], wf[i], acc[mt], 0, 0, 0);
#pragma unroll
      for (int mt = 0; mt < 4; ++mt)
#pragma unroll
        for (int r = 0; r < 4; ++r)
          gh[wv & 3][mt * 16 + (lane >> 4) * 4 + r][lane & 15] = acc[mt][r];
    } else if (t + 1 < T_) {
      s16_8 af[4][8];
      LD32(af, (unsigned long long)((const char*)xfrag + (size_t)(t + 1) * 131072) + lofs);
      VMWAIT_FENCE;
      f32_4 acc[4];
#pragma unroll
      for (int mt = 0; mt < 4; ++mt) { f32_4 z = {0.f,0.f,0.f,0.f}; acc[mt] = z; }
#pragma unroll
      for (int i = 0; i < 8; ++i)
#pragma unroll
        for (int mt = 0; mt < 4; ++mt)
          acc[mt] = __builtin_amdgcn_mfma_f32_16x16x32_bf16(af[mt][i], wf[i], acc[mt], 0, 0, 0);
#pragma unroll
      for (int mt = 0; mt < 4; ++mt)
#pragma unroll
        for (int r = 0; r < 4; ++r)
          gx[(t + 1) & 1][wv][mt * 16 + (lane >> 4) * 4 + r][lane & 15] = acc[mt][r];
    }
    __syncthreads();

    // ---- phase B: elementwise cell update on h-waves (threads 256..511)
    if (tid >= 256) {
      const int xb = t & 1;
      float g4[4];
#pragma unroll
      for (int g = 0; g < 4; ++g) {
        float s = bias4[g];
        const int row = g * 4 + ejj;
#pragma unroll
        for (int w = 0; w < 4; ++w)
          s += gx[xb][w][eb][row] + gh[w][eb][row];
        g4[g] = s;
      }
      float fg = 1.f / (1.f + __expf(-g4[0]));
      float ig = 1.f / (1.f + __expf(-g4[1]));
      float gg = 1.f - 2.f / (__expf(2.f * g4[2]) + 1.f);   // tanh, inf-safe
      float og = 1.f / (1.f + __expf(-g4[3]));
      cst  = fg * cst + ig * gg;
      hval = og * (1.f - 2.f / (__expf(2.f * cst) + 1.f));
      hvals[ejj][eb] = hval;
    }
    __syncthreads();

    // ---- phase C: wave4 publish h + ack + arrive; wave5 out store.
    if (wv == 4 && t + 1 < T_) {
      float h0 = hvals[0][lane], h1 = hvals[1][lane],
            h2 = hvals[2][lane], h3 = hvals[3][lane];
      unsigned long long pk =
          (unsigned long long)__builtin_bit_cast(unsigned short, (__bf16)h0)
        | ((unsigned long long)__builtin_bit_cast(unsigned short, (__bf16)h1) << 16)
        | ((unsigned long long)__builtin_bit_cast(unsigned short, (__bf16)h2) << 32)
        | ((unsigned long long)__builtin_bit_cast(unsigned short, (__bf16)h3) << 48);
      size_t grpi = ((size_t)(((t + 1) & 1) * 4 + (lane >> 4)) * 32 + (cu >> 3)) * 64
                    + (lane & 15) + 16 * ((cu & 7) >> 1);
      unsigned long long* dst =
          (unsigned long long*)((char*)hfrag + grpi * 16 + (cu & 1) * 8);
      __hip_atomic_store(dst, pk, __ATOMIC_RELAXED, __HIP_MEMORY_SCOPE_AGENT);
      asm volatile("s_waitcnt vmcnt(0)" ::: "memory");   // publishes acked at LLC
      if (lane == 0) atomicAdd(grp, 1u);                 // group arrival
    }
    if (wv == 5) {                       // out store, off the critical chain
      float4 o4 = make_float4(hvals[0][lane], hvals[1][lane],
                              hvals[2][lane], hvals[3][lane]);
      *(float4*)(out + ((size_t)t * 64 + lane) * 1024 + cu * 4) = o4;
    }
    __syncthreads();
  }

  // ---- h_n, c_n
  if (tid >= 256) {
    out[(size_t)T_ * 65536 + (size_t)eb * 1024 + j] = hval;
    out[(size_t)T_ * 65536 + 65536 + (size_t)eb * 1024 + j] = cst;
  }
}

extern "C" void kernel_launch(void* const* d_in, const int* in_sizes, int n_in,
                              void* d_out, int out_size, void* d_ws, size_t ws_size,
                              hipStream_t stream) {
  (void)in_sizes; (void)n_in;
  const float* X  = (const float*)d_in[0];
  const float* Wi = (const float*)d_in[1];
  const float* Wh = (const float*)d_in[2];
  const float* bi = (const float*)d_in[3];
  const float* bh = (const float*)d_in[4];
  float* out = (float*)d_out;

  char* ws = (char*)d_ws;
  const size_t W_BYTES = (size_t)256 * 64 * 64 * 8 * 2;     // 16,777,216
  const size_t H_BYTES = (size_t)2 * 4 * 32 * 64 * 8 * 2;   //    262,144
  const size_t C_BYTES = 4096;
  const size_t X_BYTES = (size_t)512 * 4 * 32 * 64 * 8 * 2; // 67,108,864

  bf16_8* wfrag = (bf16_8*)ws;
  bf16_8* hfrag = (bf16_8*)(ws + W_BYTES);
  unsigned int* ctr = (unsigned int*)(ws + W_BYTES + H_BYTES);

  bf16_8* xfrag;
  if (ws_size >= W_BYTES + H_BYTES + C_BYTES + X_BYTES) {
    xfrag = (bf16_8*)(ws + W_BYTES + H_BYTES + C_BYTES);
  } else {
    // place x-frags in the tail of d_out; out rows clobber xfrag[t'] only for
    // t' < 2t-514 < t+1 (already consumed, skew<=1); final outputs cover all.
    size_t out_bytes = (size_t)out_size * 4;
    xfrag = (bf16_8*)((char*)d_out + out_bytes - X_BYTES);
  }

  hipMemsetAsync(hfrag, 0, 131072, stream);   // zero h buffer 0 (t=0 reads it)
  hipMemsetAsync(ctr, 0, C_BYTES, stream);    // reset group counters

  hipLaunchKernelGGL(p1_xfrag, dim3(16384), dim3(256), 0, stream, X, xfrag);
  hipLaunchKernelGGL(p2_wfrag, dim3(4096), dim3(256), 0, stream, Wi, Wh, wfrag);
  hipLaunchKernelGGL(lstm_persist, dim3(256), dim3(512), 0, stream,
                     bi, bh, (const s16_8*)xfrag, (const s16_8*)wfrag,
                     (s16_8*)hfrag, out, ctr);
}

// Round 14
// 2892.722 us; speedup vs baseline: 1.1005x; 1.1005x over previous
//
#include <hip/hip_runtime.h>
#include <hip/hip_bf16.h>

typedef __bf16  bf16_8 __attribute__((ext_vector_type(8)));
typedef short   s16_8  __attribute__((ext_vector_type(8)));
typedef float   f32_4  __attribute__((ext_vector_type(4)));

#define T_ 512

// Issue 8 global_load_dwordx4 (one mt group: frag i=0..7, stride 1024B) from
// base b0 (i=0..3) and b0+4096 (i=4..7). No wait — caller waits via VMWAIT.
// Early-clobber outputs: must not alias the base-address registers.
#define LD8(d0,d1,d2,d3,d4,d5,d6,d7, BASE)                                  \
  { unsigned long long _b0 = (BASE), _b1 = (BASE) + 4096ull;                \
    asm volatile(                                                           \
      "global_load_dwordx4 %0, %8, off\n\t"                                 \
      "global_load_dwordx4 %1, %8, off offset:1024\n\t"                     \
      "global_load_dwordx4 %2, %8, off offset:2048\n\t"                     \
      "global_load_dwordx4 %3, %8, off offset:3072\n\t"                     \
      "global_load_dwordx4 %4, %9, off\n\t"                                 \
      "global_load_dwordx4 %5, %9, off offset:1024\n\t"                     \
      "global_load_dwordx4 %6, %9, off offset:2048\n\t"                     \
      "global_load_dwordx4 %7, %9, off offset:3072\n\t"                     \
      : "=&v"(d0),"=&v"(d1),"=&v"(d2),"=&v"(d3),                            \
        "=&v"(d4),"=&v"(d5),"=&v"(d6),"=&v"(d7)                             \
      : "v"(_b0), "v"(_b1)); }

// Coherent variant for h: sc0 sc1 = bypass L1/L2, read at LLC (the coherence
// point where the sc1 publishes land). Fenceless coherence (r11-proven).
#define LD8C(d0,d1,d2,d3,d4,d5,d6,d7, BASE)                                 \
  { unsigned long long _b0 = (BASE), _b1 = (BASE) + 4096ull;                \
    asm volatile(                                                           \
      "global_load_dwordx4 %0, %8, off sc0 sc1\n\t"                         \
      "global_load_dwordx4 %1, %8, off offset:1024 sc0 sc1\n\t"             \
      "global_load_dwordx4 %2, %8, off offset:2048 sc0 sc1\n\t"             \
      "global_load_dwordx4 %3, %8, off offset:3072 sc0 sc1\n\t"             \
      "global_load_dwordx4 %4, %9, off sc0 sc1\n\t"                         \
      "global_load_dwordx4 %5, %9, off offset:1024 sc0 sc1\n\t"             \
      "global_load_dwordx4 %6, %9, off offset:2048 sc0 sc1\n\t"             \
      "global_load_dwordx4 %7, %9, off offset:3072 sc0 sc1\n\t"             \
      : "=&v"(d0),"=&v"(d1),"=&v"(d2),"=&v"(d3),                            \
        "=&v"(d4),"=&v"(d5),"=&v"(d6),"=&v"(d7)                             \
      : "v"(_b0), "v"(_b1)); }

#define LD32(AF, BASE)                                                      \
  LD8(AF[0][0],AF[0][1],AF[0][2],AF[0][3],AF[0][4],AF[0][5],AF[0][6],AF[0][7], (BASE));          \
  LD8(AF[1][0],AF[1][1],AF[1][2],AF[1][3],AF[1][4],AF[1][5],AF[1][6],AF[1][7], (BASE)+32768ull); \
  LD8(AF[2][0],AF[2][1],AF[2][2],AF[2][3],AF[2][4],AF[2][5],AF[2][6],AF[2][7], (BASE)+65536ull); \
  LD8(AF[3][0],AF[3][1],AF[3][2],AF[3][3],AF[3][4],AF[3][5],AF[3][6],AF[3][7], (BASE)+98304ull);

#define LD32C(AF, BASE)                                                     \
  LD8C(AF[0][0],AF[0][1],AF[0][2],AF[0][3],AF[0][4],AF[0][5],AF[0][6],AF[0][7], (BASE));          \
  LD8C(AF[1][0],AF[1][1],AF[1][2],AF[1][3],AF[1][4],AF[1][5],AF[1][6],AF[1][7], (BASE)+32768ull); \
  LD8C(AF[2][0],AF[2][1],AF[2][2],AF[2][3],AF[2][4],AF[2][5],AF[2][6],AF[2][7], (BASE)+65536ull); \
  LD8C(AF[3][0],AF[3][1],AF[3][2],AF[3][3],AF[3][4],AF[3][5],AF[3][6],AF[3][7], (BASE)+98304ull);

// Wait for all loads, then fence the scheduler so no af-consumer (MFMA is
// register-only, NOT ordered by the "memory" clobber) hoists above it.
#define VMWAIT_FENCE                                                        \
  asm volatile("s_waitcnt vmcnt(0)" ::: "memory");                          \
  __builtin_amdgcn_sched_barrier(0)

// ---------------- P1: X fp32 [T][B][1024] -> xfrag bf16 [T][4 mt][32 kc][64 lane][8]
__global__ __launch_bounds__(256) void p1_xfrag(const float* __restrict__ X,
                                                bf16_8* __restrict__ xf) {
  size_t n = (size_t)blockIdx.x * 256 + threadIdx.x;   // 4,194,304 total
  int lane = (int)(n & 63);
  int kc   = (int)((n >> 6) & 31);
  int mt   = (int)((n >> 11) & 3);
  int t    = (int)(n >> 13);
  int b  = 16 * mt + (lane & 15);
  int i0 = 32 * kc + (lane >> 4) * 8;
  const float4* ps = (const float4*)(X + ((size_t)t * 64 + b) * 1024 + i0);
  float4 a = ps[0], c = ps[1];
  bf16_8 v;
  v[0]=(__bf16)a.x; v[1]=(__bf16)a.y; v[2]=(__bf16)a.z; v[3]=(__bf16)a.w;
  v[4]=(__bf16)c.x; v[5]=(__bf16)c.y; v[6]=(__bf16)c.z; v[7]=(__bf16)c.w;
  xf[n] = v;
}

// ---------------- P2: Wi,Wh fp32 -> wfrag bf16 [128 c][2 nt][64 kc][64 lane][8]
// Col-block c owns hcols c*8..+7, 32 W-rows = 4 gates x 8 cols.
// Within n-tile nt (gates 2nt, 2nt+1): n16 = lane&15 -> g = 2*nt + (n16>>3),
// q = n16&7, col = c*8 + q. k = 32*kc + (lane>>4)*8 + e (kc<32: Wi, else Wh).
__global__ __launch_bounds__(256) void p2_wfrag(const float* __restrict__ Wi,
                                                const float* __restrict__ Wh,
                                                bf16_8* __restrict__ wf) {
  size_t n = (size_t)blockIdx.x * 256 + threadIdx.x;   // 1,048,576 total
  int lane = (int)(n & 63);
  int kc   = (int)((n >> 6) & 63);
  int nt   = (int)((n >> 12) & 1);
  int c    = (int)(n >> 13);
  int n16 = lane & 15;
  int g   = 2 * nt + (n16 >> 3);
  int col = c * 8 + (n16 & 7);
  int k = 32 * kc + (lane >> 4) * 8;
  const float* src = (k < 1024)
      ? (Wi + ((size_t)g * 1024 + col) * 1024 + k)
      : (Wh + ((size_t)g * 1024 + col) * 1024 + (k - 1024));
  const float4* ps = (const float4*)src;
  float4 a = ps[0], cc = ps[1];
  bf16_8 v;
  v[0]=(__bf16)a.x; v[1]=(__bf16)a.y; v[2]=(__bf16)a.z; v[3]=(__bf16)a.w;
  v[4]=(__bf16)cc.x; v[5]=(__bf16)cc.y; v[6]=(__bf16)cc.z; v[7]=(__bf16)cc.w;
  wf[n] = v;
}

// ---------------- persistent LSTM: 128 blocks x 512 threads (8 waves)
// 2x column concentration vs r11: each CU owns 8 hcols (32 gate-rows), so the
// per-step h broadcast is 128 CUs x 128 KB = 16 MB (was 32) — aggregate-LLC-
// BW-bound term halves. Structure otherwise identical to r11 (best):
// Phase A: h-waves (4-7) h-GEMM(t), LLC-direct sc0sc1 loads, fenceless.
// Phase B: elementwise (threads 256..511, 2 cols each).
// Phase C: x-waves x-GEMM(t+1); wave4 publish h + arrive; wave6 relay barrier.
__global__ __launch_bounds__(512, 2) void lstm_persist(
    const float* __restrict__ bi, const float* __restrict__ bh,
    const s16_8* __restrict__ xfrag, const s16_8* __restrict__ wfrag,
    s16_8* __restrict__ hfrag, float* __restrict__ out,
    unsigned int* __restrict__ ctr)
{
  __shared__ float gx[2][4][64][33];   // x-partials, dbuf            67,584 B
  __shared__ float gh[4][64][33];      // h-partials                  33,792 B
  __shared__ float hvals[8][64];       // h gather for pack            2,048 B

  const int tid  = threadIdx.x;
  const int c    = blockIdx.x;         // col-block: hcols c*8..+7
  const int wv   = tid >> 6;
  const int lane = tid & 63;
  const bool ish = (wv >= 4);
  const unsigned long long lofs = (unsigned long long)(((wv & 3) * 8) * 1024 + lane * 16);

  // resident B-fragments of W: 2 n-tiles x 8 K-chunks = 16 regs/wave
  s16_8 wf[2][8];
#pragma unroll
  for (int nt = 0; nt < 2; ++nt)
#pragma unroll
    for (int i = 0; i < 8; ++i)
      wf[nt][i] = wfrag[(((size_t)c * 2 + nt) * 64 + wv * 8 + i) * 64 + lane];
#pragma unroll
  for (int nt = 0; nt < 2; ++nt)
#pragma unroll
    for (int i = 0; i < 8; ++i)
      asm volatile("" : "+v"(wf[nt][i]));   // pin resident

  // cell identity (threads 256..511): eb = batch, cols q = cg, cg+4
  const int et  = tid - 256;
  const int eb  = et & 63;
  const int cg  = (et >> 6) & 3;
  float biasv[2][4];
#pragma unroll
  for (int p = 0; p < 2; ++p)
#pragma unroll
    for (int g = 0; g < 4; ++g) biasv[p][g] = 0.f;
  if (tid >= 256) {
#pragma unroll
    for (int p = 0; p < 2; ++p) {
      int j = c * 8 + cg + p * 4;
#pragma unroll
      for (int g = 0; g < 4; ++g)
        biasv[p][g] = bi[g * 1024 + j] + bh[g * 1024 + j];
    }
  }
  float cst[2] = {0.f, 0.f}, hval[2] = {0.f, 0.f};

  unsigned int* grp  = ctr + (c >> 4) * 64;   // 8 group counters (16 CUs each)
  unsigned int* flag = ctr + 512;             // release flag, own line

  // ---- prologue: x-waves compute gx(0)
  if (!ish) {
    s16_8 af[4][8];
    LD32(af, (unsigned long long)(const char*)xfrag + lofs);
    VMWAIT_FENCE;
    f32_4 acc[4][2];
#pragma unroll
    for (int mt = 0; mt < 4; ++mt)
#pragma unroll
      for (int nt = 0; nt < 2; ++nt) { f32_4 z = {0.f,0.f,0.f,0.f}; acc[mt][nt] = z; }
#pragma unroll
    for (int i = 0; i < 8; ++i)
#pragma unroll
      for (int mt = 0; mt < 4; ++mt)
#pragma unroll
        for (int nt = 0; nt < 2; ++nt)
          acc[mt][nt] = __builtin_amdgcn_mfma_f32_16x16x32_bf16(af[mt][i], wf[nt][i], acc[mt][nt], 0, 0, 0);
#pragma unroll
    for (int mt = 0; mt < 4; ++mt)
#pragma unroll
      for (int nt = 0; nt < 2; ++nt)
#pragma unroll
        for (int r = 0; r < 4; ++r)
          gx[0][wv][mt * 16 + (lane >> 4) * 4 + r][nt * 16 + (lane & 15)] = acc[mt][nt][r];
  }
  __syncthreads();

  for (int t = 0; t < T_; ++t) {
    // ---- phase A: h-waves GEMM h(t-1), LLC-direct (sc0 sc1), fenceless
    if (ish) {
      s16_8 af[4][8];
      LD32C(af, (unsigned long long)((const char*)hfrag + (size_t)(t & 1) * 131072) + lofs);
      VMWAIT_FENCE;
      f32_4 acc[4][2];
#pragma unroll
      for (int mt = 0; mt < 4; ++mt)
#pragma unroll
        for (int nt = 0; nt < 2; ++nt) { f32_4 z = {0.f,0.f,0.f,0.f}; acc[mt][nt] = z; }
#pragma unroll
      for (int i = 0; i < 8; ++i)
#pragma unroll
        for (int mt = 0; mt < 4; ++mt)
#pragma unroll
          for (int nt = 0; nt < 2; ++nt)
            acc[mt][nt] = __builtin_amdgcn_mfma_f32_16x16x32_bf16(af[mt][i], wf[nt][i], acc[mt][nt], 0, 0, 0);
#pragma unroll
      for (int mt = 0; mt < 4; ++mt)
#pragma unroll
        for (int nt = 0; nt < 2; ++nt)
#pragma unroll
          for (int r = 0; r < 4; ++r)
            gh[wv & 3][mt * 16 + (lane >> 4) * 4 + r][nt * 16 + (lane & 15)] = acc[mt][nt][r];
    }
    __syncthreads();

    // ---- phase B: elementwise cell update (threads 256..511, 2 cols each)
    if (tid >= 256) {
      const int xb = t & 1;
#pragma unroll
      for (int p = 0; p < 2; ++p) {
        const int q = cg + p * 4;
        float g4[4];
#pragma unroll
        for (int g = 0; g < 4; ++g) {
          const int row = (g >> 1) * 16 + (g & 1) * 8 + q;
          float s = biasv[p][g];
#pragma unroll
          for (int w = 0; w < 4; ++w)
            s += gx[xb][w][eb][row] + gh[w][eb][row];
          g4[g] = s;
        }
        float fg = 1.f / (1.f + __expf(-g4[0]));
        float ig = 1.f / (1.f + __expf(-g4[1]));
        float gg = 1.f - 2.f / (__expf(2.f * g4[2]) + 1.f);   // tanh, inf-safe
        float og = 1.f / (1.f + __expf(-g4[3]));
        cst[p]  = fg * cst[p] + ig * gg;
        hval[p] = og * (1.f - 2.f / (__expf(2.f * cst[p]) + 1.f));
        hvals[q][eb] = hval[p];
      }
    }
    __syncthreads();

    // ---- phase C: x-waves GEMM x(t+1); wave4 publish+arrive; wave5 out;
    //      wave6 relay barrier (r11-proven: tiny fan-in, one broadcast line)
    if (!ish && t + 1 < T_) {
      s16_8 af[4][8];
      LD32(af, (unsigned long long)((const char*)xfrag + (size_t)(t + 1) * 131072) + lofs);
      VMWAIT_FENCE;
      f32_4 acc[4][2];
#pragma unroll
      for (int mt = 0; mt < 4; ++mt)
#pragma unroll
        for (int nt = 0; nt < 2; ++nt) { f32_4 z = {0.f,0.f,0.f,0.f}; acc[mt][nt] = z; }
#pragma unroll
      for (int i = 0; i < 8; ++i)
#pragma unroll
        for (int mt = 0; mt < 4; ++mt)
#pragma unroll
          for (int nt = 0; nt < 2; ++nt)
            acc[mt][nt] = __builtin_amdgcn_mfma_f32_16x16x32_bf16(af[mt][i], wf[nt][i], acc[mt][nt], 0, 0, 0);
#pragma unroll
      for (int mt = 0; mt < 4; ++mt)
#pragma unroll
        for (int nt = 0; nt < 2; ++nt)
#pragma unroll
          for (int r = 0; r < 4; ++r)
            gx[(t + 1) & 1][wv][mt * 16 + (lane >> 4) * 4 + r][nt * 16 + (lane & 15)] = acc[mt][nt][r];
    }
    if (wv == 5) {                       // out store, off the critical chain
      float4 o0 = make_float4(hvals[0][lane], hvals[1][lane],
                              hvals[2][lane], hvals[3][lane]);
      float4 o1 = make_float4(hvals[4][lane], hvals[5][lane],
                              hvals[6][lane], hvals[7][lane]);
      float* op = out + ((size_t)t * 64 + lane) * 1024 + c * 8;
      *(float4*)op = o0;
      *(float4*)(op + 4) = o1;
    }
    if (t + 1 < T_) {
      if (wv == 4) {                     // publish: 8 cols/batch = one 16B word
        float hh[8];
#pragma unroll
        for (int q = 0; q < 8; ++q) hh[q] = hvals[q][lane];
        unsigned long long pk0 =
            (unsigned long long)__builtin_bit_cast(unsigned short, (__bf16)hh[0])
          | ((unsigned long long)__builtin_bit_cast(unsigned short, (__bf16)hh[1]) << 16)
          | ((unsigned long long)__builtin_bit_cast(unsigned short, (__bf16)hh[2]) << 32)
          | ((unsigned long long)__builtin_bit_cast(unsigned short, (__bf16)hh[3]) << 48);
        unsigned long long pk1 =
            (unsigned long long)__builtin_bit_cast(unsigned short, (__bf16)hh[4])
          | ((unsigned long long)__builtin_bit_cast(unsigned short, (__bf16)hh[5]) << 16)
          | ((unsigned long long)__builtin_bit_cast(unsigned short, (__bf16)hh[6]) << 32)
          | ((unsigned long long)__builtin_bit_cast(unsigned short, (__bf16)hh[7]) << 48);
        size_t a16 = (((size_t)(((t + 1) & 1) * 4 + (lane >> 4))) * 32 + (c >> 2)) * 64
                     + (lane & 15) + 16 * (c & 3);
        unsigned long long* dst = (unsigned long long*)((char*)hfrag + a16 * 16);
        __hip_atomic_store(dst,     pk0, __ATOMIC_RELAXED, __HIP_MEMORY_SCOPE_AGENT);
        __hip_atomic_store(dst + 1, pk1, __ATOMIC_RELAXED, __HIP_MEMORY_SCOPE_AGENT);
        asm volatile("s_waitcnt vmcnt(0)" ::: "memory");   // acked at LLC
        if (lane == 0) atomicAdd(grp, 1u);
      }
      if (wv == 6) {                     // relay barrier
        const unsigned tgt = 16u * (unsigned)(t + 1);
        if (c == 0) {
          if (lane < 8) {
            unsigned int* cc = ctr + lane * 64;
            while (__hip_atomic_load(cc, __ATOMIC_RELAXED, __HIP_MEMORY_SCOPE_AGENT) < tgt)
              __builtin_amdgcn_s_sleep(1);
          }
          if (lane == 0)
            __hip_atomic_store(flag, (unsigned)(t + 1), __ATOMIC_RELAXED,
                               __HIP_MEMORY_SCOPE_AGENT);
        } else if (lane == 0) {
          while (__hip_atomic_load(flag, __ATOMIC_RELAXED, __HIP_MEMORY_SCOPE_AGENT)
                 < (unsigned)(t + 1))
            __builtin_amdgcn_s_sleep(1);
        }
      }
    }
    __syncthreads();
  }

  // ---- h_n, c_n
  if (tid >= 256) {
#pragma unroll
    for (int p = 0; p < 2; ++p) {
      int j = c * 8 + cg + p * 4;
      out[(size_t)T_ * 65536 + (size_t)eb * 1024 + j] = hval[p];
      out[(size_t)T_ * 65536 + 65536 + (size_t)eb * 1024 + j] = cst[p];
    }
  }
}

extern "C" void kernel_launch(void* const* d_in, const int* in_sizes, int n_in,
                              void* d_out, int out_size, void* d_ws, size_t ws_size,
                              hipStream_t stream) {
  (void)in_sizes; (void)n_in;
  const float* X  = (const float*)d_in[0];
  const float* Wi = (const float*)d_in[1];
  const float* Wh = (const float*)d_in[2];
  const float* bi = (const float*)d_in[3];
  const float* bh = (const float*)d_in[4];
  float* out = (float*)d_out;

  char* ws = (char*)d_ws;
  const size_t W_BYTES = (size_t)128 * 2 * 64 * 64 * 8 * 2; // 16,777,216
  const size_t H_BYTES = (size_t)2 * 4 * 32 * 64 * 8 * 2;   //    262,144
  const size_t C_BYTES = 4096;
  const size_t X_BYTES = (size_t)512 * 4 * 32 * 64 * 8 * 2; // 67,108,864

  bf16_8* wfrag = (bf16_8*)ws;
  bf16_8* hfrag = (bf16_8*)(ws + W_BYTES);
  unsigned int* ctr = (unsigned int*)(ws + W_BYTES + H_BYTES);

  bf16_8* xfrag;
  if (ws_size >= W_BYTES + H_BYTES + C_BYTES + X_BYTES) {
    xfrag = (bf16_8*)(ws + W_BYTES + H_BYTES + C_BYTES);
  } else {
    // place x-frags in the tail of d_out; out rows clobber xfrag[t'] only for
    // t' < 2t-514 < t+1 (already consumed); final outputs cover everything.
    size_t out_bytes = (size_t)out_size * 4;
    xfrag = (bf16_8*)((char*)d_out + out_bytes - X_BYTES);
  }

  hipMemsetAsync(hfrag, 0, 131072, stream);   // zero h buffer 0 (t=0 reads it)
  hipMemsetAsync(ctr, 0, C_BYTES, stream);    // reset barrier counters + flag

  hipLaunchKernelGGL(p1_xfrag, dim3(16384), dim3(256), 0, stream, X, xfrag);
  hipLaunchKernelGGL(p2_wfrag, dim3(4096), dim3(256), 0, stream, Wi, Wh, wfrag);
  hipLaunchKernelGGL(lstm_persist, dim3(128), dim3(512), 0, stream,
                     bi, bh, (const s16_8*)xfrag, (const s16_8*)wfrag,
                     (s16_8*)hfrag, out, ctr);
}

// Round 15
// 2585.990 us; speedup vs baseline: 1.2310x; 1.1186x over previous
//
#include <hip/hip_runtime.h>
#include <hip/hip_bf16.h>

typedef __bf16  bf16_8 __attribute__((ext_vector_type(8)));
typedef short   s16_8  __attribute__((ext_vector_type(8)));
typedef float   f32_4  __attribute__((ext_vector_type(4)));

#define T_ 512

// Issue 8 global_load_dwordx4 (one mt group: frag i=0..7, stride 1024B) from
// base b0 (i=0..3) and b0+4096 (i=4..7). No wait — caller waits via VMWAIT.
#define LD8(d0,d1,d2,d3,d4,d5,d6,d7, BASE)                                  \
  { unsigned long long _b0 = (BASE), _b1 = (BASE) + 4096ull;                \
    asm volatile(                                                           \
      "global_load_dwordx4 %0, %8, off\n\t"                                 \
      "global_load_dwordx4 %1, %8, off offset:1024\n\t"                     \
      "global_load_dwordx4 %2, %8, off offset:2048\n\t"                     \
      "global_load_dwordx4 %3, %8, off offset:3072\n\t"                     \
      "global_load_dwordx4 %4, %9, off\n\t"                                 \
      "global_load_dwordx4 %5, %9, off offset:1024\n\t"                     \
      "global_load_dwordx4 %6, %9, off offset:2048\n\t"                     \
      "global_load_dwordx4 %7, %9, off offset:3072\n\t"                     \
      : "=&v"(d0),"=&v"(d1),"=&v"(d2),"=&v"(d3),                            \
        "=&v"(d4),"=&v"(d5),"=&v"(d6),"=&v"(d7)                             \
      : "v"(_b0), "v"(_b1)); }

// Coherent 4-load variant (one mt group, 4 chunks): sc0 sc1 = LLC-direct,
// coherent with sc1 publishes, no fence needed (r11-proven).
#define LD4C(d0,d1,d2,d3, BASE)                                             \
  { unsigned long long _b0 = (BASE);                                        \
    asm volatile(                                                           \
      "global_load_dwordx4 %0, %4, off sc0 sc1\n\t"                         \
      "global_load_dwordx4 %1, %4, off offset:1024 sc0 sc1\n\t"             \
      "global_load_dwordx4 %2, %4, off offset:2048 sc0 sc1\n\t"             \
      "global_load_dwordx4 %3, %4, off offset:3072 sc0 sc1\n\t"             \
      : "=&v"(d0),"=&v"(d1),"=&v"(d2),"=&v"(d3)                             \
      : "v"(_b0)); }

#define LD32(AF, BASE)                                                      \
  LD8(AF[0][0],AF[0][1],AF[0][2],AF[0][3],AF[0][4],AF[0][5],AF[0][6],AF[0][7], (BASE));          \
  LD8(AF[1][0],AF[1][1],AF[1][2],AF[1][3],AF[1][4],AF[1][5],AF[1][6],AF[1][7], (BASE)+32768ull); \
  LD8(AF[2][0],AF[2][1],AF[2][2],AF[2][3],AF[2][4],AF[2][5],AF[2][6],AF[2][7], (BASE)+65536ull); \
  LD8(AF[3][0],AF[3][1],AF[3][2],AF[3][3],AF[3][4],AF[3][5],AF[3][6],AF[3][7], (BASE)+98304ull);

// 16 coherent loads: 4 mt groups x 4 chunks (this wave's h K-slice)
#define LD16C4(AF, BASE)                                                    \
  LD4C(AF[0][0],AF[0][1],AF[0][2],AF[0][3], (BASE));                        \
  LD4C(AF[1][0],AF[1][1],AF[1][2],AF[1][3], (BASE)+32768ull);               \
  LD4C(AF[2][0],AF[2][1],AF[2][2],AF[2][3], (BASE)+65536ull);               \
  LD4C(AF[3][0],AF[3][1],AF[3][2],AF[3][3], (BASE)+98304ull);

// Wait for all loads, then fence the scheduler so no af-consumer (MFMA is
// register-only, NOT ordered by the "memory" clobber) hoists above it.
#define VMWAIT_FENCE                                                        \
  asm volatile("s_waitcnt vmcnt(0)" ::: "memory");                          \
  __builtin_amdgcn_sched_barrier(0)

// ---------------- P1: X fp32 [T][B][1024] -> xfrag bf16 [T][4 mt][32 kc][64 lane][8]
__global__ __launch_bounds__(256) void p1_xfrag(const float* __restrict__ X,
                                                bf16_8* __restrict__ xf) {
  size_t n = (size_t)blockIdx.x * 256 + threadIdx.x;   // 4,194,304 total
  int lane = (int)(n & 63);
  int kc   = (int)((n >> 6) & 31);
  int mt   = (int)((n >> 11) & 3);
  int t    = (int)(n >> 13);
  int b  = 16 * mt + (lane & 15);
  int i0 = 32 * kc + (lane >> 4) * 8;
  const float4* ps = (const float4*)(X + ((size_t)t * 64 + b) * 1024 + i0);
  float4 a = ps[0], c = ps[1];
  bf16_8 v;
  v[0]=(__bf16)a.x; v[1]=(__bf16)a.y; v[2]=(__bf16)a.z; v[3]=(__bf16)a.w;
  v[4]=(__bf16)c.x; v[5]=(__bf16)c.y; v[6]=(__bf16)c.z; v[7]=(__bf16)c.w;
  xf[n] = v;
}

// ---------------- P2: Wi,Wh fp32 -> wfrag bf16 [256 cu][64 kc][64 lane][8]
__global__ __launch_bounds__(256) void p2_wfrag(const float* __restrict__ Wi,
                                                const float* __restrict__ Wh,
                                                bf16_8* __restrict__ wf) {
  size_t n = (size_t)blockIdx.x * 256 + threadIdx.x;   // 1,048,576 total
  int lane = (int)(n & 63);
  int kc   = (int)((n >> 6) & 63);
  int cu   = (int)(n >> 12);
  int n16 = lane & 15;
  int g  = n16 >> 2;
  int jj = n16 & 3;
  int col = 4 * cu + jj;
  int k = 32 * kc + (lane >> 4) * 8;
  const float* src = (k < 1024)
      ? (Wi + ((size_t)g * 1024 + col) * 1024 + k)
      : (Wh + ((size_t)g * 1024 + col) * 1024 + (k - 1024));
  const float4* ps = (const float4*)src;
  float4 a = ps[0], c = ps[1];
  bf16_8 v;
  v[0]=(__bf16)a.x; v[1]=(__bf16)a.y; v[2]=(__bf16)a.z; v[3]=(__bf16)a.w;
  v[4]=(__bf16)c.x; v[5]=(__bf16)c.y; v[6]=(__bf16)c.z; v[7]=(__bf16)c.w;
  wf[n] = v;
}

// ---------------- persistent LSTM: 256 blocks x 512 threads (8 waves)
// vs r11 (best): (1) h-GEMM split over ALL 8 waves (4 K-chunks each) —
// doubles load-issue parallelism on the phase-A critical path; (2) publish
// moved into phase B (each cell wave stores its own column, 2B sc1 stores);
// the B-end __syncthreads drains all acks, so wave4's arrive in phase C is
// immediate (no vmcnt wait on the serial sync chain).
__global__ __launch_bounds__(512, 2) void lstm_persist(
    const float* __restrict__ bi, const float* __restrict__ bh,
    const s16_8* __restrict__ xfrag, const s16_8* __restrict__ wfrag,
    s16_8* __restrict__ hfrag, float* __restrict__ out,
    unsigned int* __restrict__ ctr)
{
  __shared__ float gx[2][4][64][17];   // x-partials, dbuf            34,816 B
  __shared__ float gh[8][64][17];      // h-partials (8 waves)        34,816 B
  __shared__ float hvals[4][64];       // h gather for out-store       1,024 B

  const int tid  = threadIdx.x;
  const int cu   = blockIdx.x;
  const int wv   = tid >> 6;
  const int lane = tid & 63;
  const bool ish = (wv >= 4);

  // resident W B-frags: h-slice (4 chunks) for ALL waves; x-slice (8 chunks)
  // for x-waves only.
  s16_8 whf[4];
#pragma unroll
  for (int i = 0; i < 4; ++i)
    whf[i] = wfrag[((size_t)cu * 64 + 32 + wv * 4 + i) * 64 + lane];
#pragma unroll
  for (int i = 0; i < 4; ++i)
    asm volatile("" : "+v"(whf[i]));
  s16_8 wxf[8];
  if (!ish) {
#pragma unroll
    for (int i = 0; i < 8; ++i)
      wxf[i] = wfrag[((size_t)cu * 64 + wv * 8 + i) * 64 + lane];
#pragma unroll
    for (int i = 0; i < 8; ++i)
      asm volatile("" : "+v"(wxf[i]));
  }

  // elementwise identity (threads 256..511): eb = batch, ejj = column-in-block
  const int et  = tid - 256;
  const int eb  = et & 63;
  const int ejj = (et >> 6) & 3;
  const int j   = cu * 4 + ejj;
  float bias4[4] = {0.f, 0.f, 0.f, 0.f};
  if (tid >= 256) {
#pragma unroll
    for (int g = 0; g < 4; ++g) bias4[g] = bi[g * 1024 + j] + bh[g * 1024 + j];
  }
  float cst = 0.f, hval = 0.f;

  unsigned int* grp  = ctr + (cu >> 5) * 64;   // 8 group counters, 256 B apart
  unsigned int* flag = ctr + 512;              // release flag, own line

  // ---- prologue: x-waves compute gx(0)
  if (!ish) {
    s16_8 af[4][8];
    LD32(af, (unsigned long long)(const char*)xfrag
             + (unsigned)(wv * 8192 + lane * 16));
    VMWAIT_FENCE;
    f32_4 acc[4];
#pragma unroll
    for (int mt = 0; mt < 4; ++mt) { f32_4 z = {0.f,0.f,0.f,0.f}; acc[mt] = z; }
#pragma unroll
    for (int i = 0; i < 8; ++i)
#pragma unroll
      for (int mt = 0; mt < 4; ++mt)
        acc[mt] = __builtin_amdgcn_mfma_f32_16x16x32_bf16(af[mt][i], wxf[i], acc[mt], 0, 0, 0);
#pragma unroll
    for (int mt = 0; mt < 4; ++mt)
#pragma unroll
      for (int r = 0; r < 4; ++r)
        gx[0][wv][mt * 16 + (lane >> 4) * 4 + r][lane & 15] = acc[mt][r];
  }
  __syncthreads();

  for (int t = 0; t < T_; ++t) {
    // ---- phase A: ALL 8 waves h-GEMM h(t-1), 4 K-chunks each (LLC-direct)
    {
      s16_8 af[4][4];
      LD16C4(af, (unsigned long long)((const char*)hfrag + (size_t)(t & 1) * 131072)
                 + (unsigned)(wv * 4096 + lane * 16));
      VMWAIT_FENCE;
      f32_4 acc[4];
#pragma unroll
      for (int mt = 0; mt < 4; ++mt) { f32_4 z = {0.f,0.f,0.f,0.f}; acc[mt] = z; }
#pragma unroll
      for (int i = 0; i < 4; ++i)
#pragma unroll
        for (int mt = 0; mt < 4; ++mt)
          acc[mt] = __builtin_amdgcn_mfma_f32_16x16x32_bf16(af[mt][i], whf[i], acc[mt], 0, 0, 0);
#pragma unroll
      for (int mt = 0; mt < 4; ++mt)
#pragma unroll
        for (int r = 0; r < 4; ++r)
          gh[wv][mt * 16 + (lane >> 4) * 4 + r][lane & 15] = acc[mt][r];
    }
    __syncthreads();

    // ---- phase B: cell update (threads 256..511) + per-column publish.
    // B-end __syncthreads drains every wave's vmcnt (HW counter covers the
    // asm stores) -> all publishes acked at LLC before anyone leaves B.
    if (tid >= 256) {
      const int xb = t & 1;
      float g4[4];
#pragma unroll
      for (int g = 0; g < 4; ++g) {
        float s = bias4[g];
        const int row = g * 4 + ejj;
#pragma unroll
        for (int w = 0; w < 4; ++w) s += gx[xb][w][eb][row];
#pragma unroll
        for (int w = 0; w < 8; ++w) s += gh[w][eb][row];
        g4[g] = s;
      }
      float fg = 1.f / (1.f + __expf(-g4[0]));
      float ig = 1.f / (1.f + __expf(-g4[1]));
      float gg = 1.f - 2.f / (__expf(2.f * g4[2]) + 1.f);   // tanh, inf-safe
      float og = 1.f / (1.f + __expf(-g4[3]));
      cst  = fg * cst + ig * gg;
      hval = og * (1.f - 2.f / (__expf(2.f * cst) + 1.f));
      hvals[ejj][eb] = hval;
      if (t + 1 < T_) {                 // publish own column (2B, agent/LLC)
        size_t grpi = ((size_t)(((t + 1) & 1) * 4 + (eb >> 4)) * 32 + (cu >> 3)) * 64
                      + (eb & 15) + 16 * ((cu & 7) >> 1);
        unsigned long long dst = (unsigned long long)(char*)hfrag
                                 + grpi * 16 + (cu & 1) * 8 + ejj * 2;
        unsigned hv16 = (unsigned)__builtin_bit_cast(unsigned short, (__bf16)hval);
        asm volatile("global_store_short %0, %1, off sc1"
                     :: "v"(dst), "v"(hv16) : "memory");
      }
    }
    __syncthreads();                     // drains publish acks (per-wave vmcnt)

    // ---- phase C: x-waves x-GEMM(t+1); wave4 immediate arrive; wave5 out;
    //      wave6 relay barrier (r11-proven: tiny fan-in, one broadcast line).
    if (!ish && t + 1 < T_) {
      s16_8 af[4][8];
      LD32(af, (unsigned long long)((const char*)xfrag + (size_t)(t + 1) * 131072)
               + (unsigned)(wv * 8192 + lane * 16));
      VMWAIT_FENCE;
      f32_4 acc[4];
#pragma unroll
      for (int mt = 0; mt < 4; ++mt) { f32_4 z = {0.f,0.f,0.f,0.f}; acc[mt] = z; }
#pragma unroll
      for (int i = 0; i < 8; ++i)
#pragma unroll
        for (int mt = 0; mt < 4; ++mt)
          acc[mt] = __builtin_amdgcn_mfma_f32_16x16x32_bf16(af[mt][i], wxf[i], acc[mt], 0, 0, 0);
#pragma unroll
      for (int mt = 0; mt < 4; ++mt)
#pragma unroll
        for (int r = 0; r < 4; ++r)
          gx[(t + 1) & 1][wv][mt * 16 + (lane >> 4) * 4 + r][lane & 15] = acc[mt][r];
    }
    if (wv == 5) {                       // out store, off the critical chain
      float4 o4 = make_float4(hvals[0][lane], hvals[1][lane],
                              hvals[2][lane], hvals[3][lane]);
      *(float4*)(out + ((size_t)t * 64 + lane) * 1024 + cu * 4) = o4;
    }
    if (t + 1 < T_) {
      if (wv == 4 && lane == 0)
        atomicAdd(grp, 1u);              // publishes already certified by B-sync
      if (wv == 6) {                     // relay barrier
        const unsigned tgt = 32u * (unsigned)(t + 1);
        if (cu == 0) {
          if (lane < 8) {
            unsigned int* cc = ctr + lane * 64;
            while (__hip_atomic_load(cc, __ATOMIC_RELAXED, __HIP_MEMORY_SCOPE_AGENT) < tgt)
              __builtin_amdgcn_s_sleep(1);
          }
          if (lane == 0)
            __hip_atomic_store(flag, (unsigned)(t + 1), __ATOMIC_RELAXED,
                               __HIP_MEMORY_SCOPE_AGENT);
        } else if (lane == 0) {
          while (__hip_atomic_load(flag, __ATOMIC_RELAXED, __HIP_MEMORY_SCOPE_AGENT)
                 < (unsigned)(t + 1))
            __builtin_amdgcn_s_sleep(1);
        }
      }
    }
    __syncthreads();
  }

  // ---- h_n, c_n
  if (tid >= 256) {
    out[(size_t)T_ * 65536 + (size_t)eb * 1024 + j] = hval;
    out[(size_t)T_ * 65536 + 65536 + (size_t)eb * 1024 + j] = cst;
  }
}

extern "C" void kernel_launch(void* const* d_in, const int* in_sizes, int n_in,
                              void* d_out, int out_size, void* d_ws, size_t ws_size,
                              hipStream_t stream) {
  (void)in_sizes; (void)n_in;
  const float* X  = (const float*)d_in[0];
  const float* Wi = (const float*)d_in[1];
  const float* Wh = (const float*)d_in[2];
  const float* bi = (const float*)d_in[3];
  const float* bh = (const float*)d_in[4];
  float* out = (float*)d_out;

  char* ws = (char*)d_ws;
  const size_t W_BYTES = (size_t)256 * 64 * 64 * 8 * 2;     // 16,777,216
  const size_t H_BYTES = (size_t)2 * 4 * 32 * 64 * 8 * 2;   //    262,144
  const size_t C_BYTES = 4096;
  const size_t X_BYTES = (size_t)512 * 4 * 32 * 64 * 8 * 2; // 67,108,864

  bf16_8* wfrag = (bf16_8*)ws;
  bf16_8* hfrag = (bf16_8*)(ws + W_BYTES);
  unsigned int* ctr = (unsigned int*)(ws + W_BYTES + H_BYTES);

  bf16_8* xfrag;
  if (ws_size >= W_BYTES + H_BYTES + C_BYTES + X_BYTES) {
    xfrag = (bf16_8*)(ws + W_BYTES + H_BYTES + C_BYTES);
  } else {
    // place x-frags in the tail of d_out; out rows clobber xfrag[t'] only for
    // t' < 2t-514 < t+1 (already consumed); final outputs cover everything.
    size_t out_bytes = (size_t)out_size * 4;
    xfrag = (bf16_8*)((char*)d_out + out_bytes - X_BYTES);
  }

  hipMemsetAsync(hfrag, 0, 131072, stream);   // zero h buffer 0 (t=0 reads it)
  hipMemsetAsync(ctr, 0, C_BYTES, stream);    // reset barrier counters + flag

  hipLaunchKernelGGL(p1_xfrag, dim3(16384), dim3(256), 0, stream, X, xfrag);
  hipLaunchKernelGGL(p2_wfrag, dim3(4096), dim3(256), 0, stream, Wi, Wh, wfrag);
  hipLaunchKernelGGL(lstm_persist, dim3(256), dim3(512), 0, stream,
                     bi, bh, (const s16_8*)xfrag, (const s16_8*)wfrag,
                     (s16_8*)hfrag, out, ctr);
}

// Round 16
// 2474.322 us; speedup vs baseline: 1.2866x; 1.0451x over previous
//
#include <hip/hip_runtime.h>
#include <hip/hip_bf16.h>

typedef __bf16  bf16_8 __attribute__((ext_vector_type(8)));
typedef short   s16_8  __attribute__((ext_vector_type(8)));
typedef float   f32_4  __attribute__((ext_vector_type(4)));

#define T_ 512

// Issue 8 global_load_dwordx4 (stride 1024B) from b0 (i=0..3), b0+4096 (4..7).
#define LD8(d0,d1,d2,d3,d4,d5,d6,d7, BASE)                                  \
  { unsigned long long _b0 = (BASE), _b1 = (BASE) + 4096ull;                \
    asm volatile(                                                           \
      "global_load_dwordx4 %0, %8, off\n\t"                                 \
      "global_load_dwordx4 %1, %8, off offset:1024\n\t"                     \
      "global_load_dwordx4 %2, %8, off offset:2048\n\t"                     \
      "global_load_dwordx4 %3, %8, off offset:3072\n\t"                     \
      "global_load_dwordx4 %4, %9, off\n\t"                                 \
      "global_load_dwordx4 %5, %9, off offset:1024\n\t"                     \
      "global_load_dwordx4 %6, %9, off offset:2048\n\t"                     \
      "global_load_dwordx4 %7, %9, off offset:3072\n\t"                     \
      : "=&v"(d0),"=&v"(d1),"=&v"(d2),"=&v"(d3),                            \
        "=&v"(d4),"=&v"(d5),"=&v"(d6),"=&v"(d7)                             \
      : "v"(_b0), "v"(_b1)); }

// Coherent 4-load (one mt group, 4 chunks): sc0 sc1 = LLC-direct (r11-proven).
#define LD4C(d0,d1,d2,d3, BASE)                                             \
  { unsigned long long _b0 = (BASE);                                        \
    asm volatile(                                                           \
      "global_load_dwordx4 %0, %4, off sc0 sc1\n\t"                         \
      "global_load_dwordx4 %1, %4, off offset:1024 sc0 sc1\n\t"             \
      "global_load_dwordx4 %2, %4, off offset:2048 sc0 sc1\n\t"             \
      "global_load_dwordx4 %3, %4, off offset:3072 sc0 sc1\n\t"             \
      : "=&v"(d0),"=&v"(d1),"=&v"(d2),"=&v"(d3)                             \
      : "v"(_b0)); }

#define LD32(AF, BASE)                                                      \
  LD8(AF[0][0],AF[0][1],AF[0][2],AF[0][3],AF[0][4],AF[0][5],AF[0][6],AF[0][7], (BASE));          \
  LD8(AF[1][0],AF[1][1],AF[1][2],AF[1][3],AF[1][4],AF[1][5],AF[1][6],AF[1][7], (BASE)+32768ull); \
  LD8(AF[2][0],AF[2][1],AF[2][2],AF[2][3],AF[2][4],AF[2][5],AF[2][6],AF[2][7], (BASE)+65536ull); \
  LD8(AF[3][0],AF[3][1],AF[3][2],AF[3][3],AF[3][4],AF[3][5],AF[3][6],AF[3][7], (BASE)+98304ull);

#define LD16C4(AF, BASE)                                                    \
  LD4C(AF[0][0],AF[0][1],AF[0][2],AF[0][3], (BASE));                        \
  LD4C(AF[1][0],AF[1][1],AF[1][2],AF[1][3], (BASE)+32768ull);               \
  LD4C(AF[2][0],AF[2][1],AF[2][2],AF[2][3], (BASE)+65536ull);               \
  LD4C(AF[3][0],AF[3][1],AF[3][2],AF[3][3], (BASE)+98304ull);

#define VMWAIT_FENCE                                                        \
  asm volatile("s_waitcnt vmcnt(0)" ::: "memory");                          \
  __builtin_amdgcn_sched_barrier(0)

// ---------------- P1: X fp32 [T][B][1024] -> xfrag bf16 [T][4 mt][32 kc][64 lane][8]
__global__ __launch_bounds__(256) void p1_xfrag(const float* __restrict__ X,
                                                bf16_8* __restrict__ xf) {
  size_t n = (size_t)blockIdx.x * 256 + threadIdx.x;   // 4,194,304 total
  int lane = (int)(n & 63);
  int kc   = (int)((n >> 6) & 31);
  int mt   = (int)((n >> 11) & 3);
  int t    = (int)(n >> 13);
  int b  = 16 * mt + (lane & 15);
  int i0 = 32 * kc + (lane >> 4) * 8;
  const float4* ps = (const float4*)(X + ((size_t)t * 64 + b) * 1024 + i0);
  float4 a = ps[0], c = ps[1];
  bf16_8 v;
  v[0]=(__bf16)a.x; v[1]=(__bf16)a.y; v[2]=(__bf16)a.z; v[3]=(__bf16)a.w;
  v[4]=(__bf16)c.x; v[5]=(__bf16)c.y; v[6]=(__bf16)c.z; v[7]=(__bf16)c.w;
  xf[n] = v;
}

// ---------------- P2: Wi,Wh fp32 -> wfrag bf16 [256 cu][64 kc][64 lane][8]
__global__ __launch_bounds__(256) void p2_wfrag(const float* __restrict__ Wi,
                                                const float* __restrict__ Wh,
                                                bf16_8* __restrict__ wf) {
  size_t n = (size_t)blockIdx.x * 256 + threadIdx.x;   // 1,048,576 total
  int lane = (int)(n & 63);
  int kc   = (int)((n >> 6) & 63);
  int cu   = (int)(n >> 12);
  int n16 = lane & 15;
  int g  = n16 >> 2;
  int jj = n16 & 3;
  int col = 4 * cu + jj;
  int k = 32 * kc + (lane >> 4) * 8;
  const float* src = (k < 1024)
      ? (Wi + ((size_t)g * 1024 + col) * 1024 + k)
      : (Wh + ((size_t)g * 1024 + col) * 1024 + (k - 1024));
  const float4* ps = (const float4*)src;
  float4 a = ps[0], c = ps[1];
  bf16_8 v;
  v[0]=(__bf16)a.x; v[1]=(__bf16)a.y; v[2]=(__bf16)a.z; v[3]=(__bf16)a.w;
  v[4]=(__bf16)c.x; v[5]=(__bf16)c.y; v[6]=(__bf16)c.z; v[7]=(__bf16)c.w;
  wf[n] = v;
}

// ---------------- persistent LSTM: 256 blocks x 512 threads, ONE sync/step.
// A: all 8 waves: self-gate on flags[wv] >= t -> h-GEMM slice (LLC-direct)
//    -> gh[wv].  __syncthreads (the only block barrier).
// B (concurrent):
//   cell waves 4-7 (ejj=et&3, eb=et>>2): cell -> shfl-pack -> 8B sc1 publish
//     -> vmcnt ack -> LDS arrive; wave4 relays ONE global arrive per CU.
//   x-waves 0-3: out(t-1) float4 stores + x-GEMM(t+1) -> gx[(t+1)&1];
//     block0/wave0 certifies 8 group counters -> fans out 8 flag copies.
// Induction: flags(t+1) => all cell(t) publishes acked => all gh/gx(t) reads
// done => A(t+1) writes are race-free; skew<=1 so 2-slot buffers suffice.
__global__ __launch_bounds__(512, 2) void lstm_persist(
    const float* __restrict__ bi, const float* __restrict__ bh,
    const s16_8* __restrict__ xfrag, const s16_8* __restrict__ wfrag,
    s16_8* __restrict__ hfrag, float* __restrict__ out,
    unsigned int* __restrict__ ctr)
{
  __shared__ float gx[2][4][64][17];    // x-partials, dbuf           34,816 B
  __shared__ float gh[8][64][17];       // h-partials (8 waves)       34,816 B
  __shared__ float hvals[2][4][64];     // h results, dbuf             2,048 B
  __shared__ unsigned cell_done;        // intra-block arrive counter

  const int tid  = threadIdx.x;
  const int cu   = blockIdx.x;
  const int wv   = tid >> 6;
  const int lane = tid & 63;
  const bool ish = (wv >= 4);

  // resident W B-frags: h-slice (4 chunks) all waves; x-slice x-waves only
  s16_8 whf[4];
#pragma unroll
  for (int i = 0; i < 4; ++i)
    whf[i] = wfrag[((size_t)cu * 64 + 32 + wv * 4 + i) * 64 + lane];
#pragma unroll
  for (int i = 0; i < 4; ++i) asm volatile("" : "+v"(whf[i]));
  s16_8 wxf[8];
  if (!ish) {
#pragma unroll
    for (int i = 0; i < 8; ++i)
      wxf[i] = wfrag[((size_t)cu * 64 + wv * 8 + i) * 64 + lane];
#pragma unroll
    for (int i = 0; i < 8; ++i) asm volatile("" : "+v"(wxf[i]));
  }

  // cell identity (threads 256..511): 4 consecutive lanes = 4 cols of 1 batch
  const int et  = tid - 256;
  const int ejj = et & 3;
  const int eb  = et >> 2;
  const int j   = cu * 4 + ejj;
  float bias4[4] = {0.f, 0.f, 0.f, 0.f};
  if (ish) {
#pragma unroll
    for (int g = 0; g < 4; ++g) bias4[g] = bi[g * 1024 + j] + bh[g * 1024 + j];
  }
  float cst = 0.f, hval = 0.f;

  unsigned int* grp = ctr + (cu >> 5) * 64;   // 8 group counters, 256 B apart
  unsigned int* flg = ctr + 1024 + wv * 64;   // this wave's flag copy

  if (tid == 0) cell_done = 0u;

  // ---- prologue: x-waves compute gx(0)
  if (!ish) {
    s16_8 af[4][8];
    LD32(af, (unsigned long long)(const char*)xfrag
             + (unsigned)(wv * 8192 + lane * 16));
    VMWAIT_FENCE;
    f32_4 acc[4];
#pragma unroll
    for (int mt = 0; mt < 4; ++mt) { f32_4 z = {0.f,0.f,0.f,0.f}; acc[mt] = z; }
#pragma unroll
    for (int i = 0; i < 8; ++i)
#pragma unroll
      for (int mt = 0; mt < 4; ++mt)
        acc[mt] = __builtin_amdgcn_mfma_f32_16x16x32_bf16(af[mt][i], wxf[i], acc[mt], 0, 0, 0);
#pragma unroll
    for (int mt = 0; mt < 4; ++mt)
#pragma unroll
      for (int r = 0; r < 4; ++r)
        gx[0][wv][mt * 16 + (lane >> 4) * 4 + r][lane & 15] = acc[mt][r];
  }
  __syncthreads();

  for (int t = 0; t < T_; ++t) {
    // ---- phase A: self-gate, then all 8 waves h-GEMM h(t-1) (LLC-direct)
    if (t > 0) {
      if (lane == 0) {
        while (__hip_atomic_load(flg, __ATOMIC_RELAXED, __HIP_MEMORY_SCOPE_AGENT)
               < (unsigned)t)
          __builtin_amdgcn_s_sleep(1);
      }
      __builtin_amdgcn_sched_barrier(0);   // h loads may not hoist above gate
    }
    {
      s16_8 af[4][4];
      LD16C4(af, (unsigned long long)((const char*)hfrag + (size_t)(t & 1) * 131072)
                 + (unsigned)(wv * 4096 + lane * 16));
      VMWAIT_FENCE;
      f32_4 acc[4];
#pragma unroll
      for (int mt = 0; mt < 4; ++mt) { f32_4 z = {0.f,0.f,0.f,0.f}; acc[mt] = z; }
#pragma unroll
      for (int i = 0; i < 4; ++i)
#pragma unroll
        for (int mt = 0; mt < 4; ++mt)
          acc[mt] = __builtin_amdgcn_mfma_f32_16x16x32_bf16(af[mt][i], whf[i], acc[mt], 0, 0, 0);
#pragma unroll
      for (int mt = 0; mt < 4; ++mt)
#pragma unroll
        for (int r = 0; r < 4; ++r)
          gh[wv][mt * 16 + (lane >> 4) * 4 + r][lane & 15] = acc[mt][r];
    }
    __syncthreads();                       // THE one block barrier per step

    // ---- B-region (no further block syncs)
    if (ish) {
      // cell update
      const int xb = t & 1;
      float g4[4];
#pragma unroll
      for (int g = 0; g < 4; ++g) {
        float s = bias4[g];
        const int row = g * 4 + ejj;
#pragma unroll
        for (int w = 0; w < 4; ++w) s += gx[xb][w][eb][row];
#pragma unroll
        for (int w = 0; w < 8; ++w) s += gh[w][eb][row];
        g4[g] = s;
      }
      float fg = 1.f / (1.f + __expf(-g4[0]));
      float ig = 1.f / (1.f + __expf(-g4[1]));
      float gg = 1.f - 2.f / (__expf(2.f * g4[2]) + 1.f);   // tanh, inf-safe
      float og = 1.f / (1.f + __expf(-g4[3]));
      cst  = fg * cst + ig * gg;
      hval = og * (1.f - 2.f / (__expf(2.f * cst) + 1.f));
      hvals[t & 1][ejj][eb] = hval;

      if (t + 1 < T_) {
        // shfl-pack 4 cols of this batch -> one 8B agent store per 4 lanes
        int base = lane & ~3;
        float p0 = __shfl(hval, base);
        float p1 = __shfl(hval, base + 1);
        float p2 = __shfl(hval, base + 2);
        float p3 = __shfl(hval, base + 3);
        if ((lane & 3) == 0) {
          unsigned long long pk =
              (unsigned long long)__builtin_bit_cast(unsigned short, (__bf16)p0)
            | ((unsigned long long)__builtin_bit_cast(unsigned short, (__bf16)p1) << 16)
            | ((unsigned long long)__builtin_bit_cast(unsigned short, (__bf16)p2) << 32)
            | ((unsigned long long)__builtin_bit_cast(unsigned short, (__bf16)p3) << 48);
          size_t grpi = ((size_t)(((t + 1) & 1) * 4 + (eb >> 4)) * 32 + (cu >> 3)) * 64
                        + (eb & 15) + 16 * ((cu & 7) >> 1);
          unsigned long long* dst =
              (unsigned long long*)((char*)hfrag + grpi * 16 + (cu & 1) * 8);
          __hip_atomic_store(dst, pk, __ATOMIC_RELAXED, __HIP_MEMORY_SCOPE_AGENT);
        }
        asm volatile("s_waitcnt vmcnt(0)" ::: "memory");   // own publish acked
        if (lane == 0)
          __hip_atomic_fetch_add(&cell_done, 1u, __ATOMIC_RELAXED,
                                 __HIP_MEMORY_SCOPE_WORKGROUP);
        if (wv == 4 && lane == 0) {        // single global arrive per CU
          while (__hip_atomic_load(&cell_done, __ATOMIC_RELAXED,
                                   __HIP_MEMORY_SCOPE_WORKGROUP) < 4u * (unsigned)(t + 1)) {}
          atomicAdd(grp, 1u);
        }
      }
    } else {
      // out(t-1), coalesced float4 (lanes 0-15 per wave, 16 rows each)
      if (t > 0 && lane < 16) {
        const int s = (t - 1) & 1;
        const int row = wv * 16 + lane;
        float4 o4 = make_float4(hvals[s][0][row], hvals[s][1][row],
                                hvals[s][2][row], hvals[s][3][row]);
        *(float4*)(out + ((size_t)(t - 1) * 64 + row) * 1024 + cu * 4) = o4;
      }
      // x-GEMM(t+1) into gx[(t+1)&1] — overlaps cell + barrier chain
      if (t + 1 < T_) {
        s16_8 af[4][8];
        LD32(af, (unsigned long long)((const char*)xfrag + (size_t)(t + 1) * 131072)
                 + (unsigned)(wv * 8192 + lane * 16));
        VMWAIT_FENCE;
        f32_4 acc[4];
#pragma unroll
        for (int mt = 0; mt < 4; ++mt) { f32_4 z = {0.f,0.f,0.f,0.f}; acc[mt] = z; }
#pragma unroll
        for (int i = 0; i < 8; ++i)
#pragma unroll
          for (int mt = 0; mt < 4; ++mt)
            acc[mt] = __builtin_amdgcn_mfma_f32_16x16x32_bf16(af[mt][i], wxf[i], acc[mt], 0, 0, 0);
#pragma unroll
        for (int mt = 0; mt < 4; ++mt)
#pragma unroll
          for (int r = 0; r < 4; ++r)
            gx[(t + 1) & 1][wv][mt * 16 + (lane >> 4) * 4 + r][lane & 15] = acc[mt][r];
      }
      // block0/wave0: certify 8 group counters, fan out 8 flag copies
      if (cu == 0 && wv == 0 && t + 1 < T_) {
        if (lane < 8) {
          unsigned int* cc = ctr + lane * 64;
          while (__hip_atomic_load(cc, __ATOMIC_RELAXED, __HIP_MEMORY_SCOPE_AGENT)
                 < 32u * (unsigned)(t + 1))
            __builtin_amdgcn_s_sleep(1);
          // lockstep: store executes only after ALL 8 lanes' polls exit
          __hip_atomic_store(ctr + 1024 + lane * 64, (unsigned)(t + 1),
                             __ATOMIC_RELAXED, __HIP_MEMORY_SCOPE_AGENT);
        }
      }
    }
  }

  __syncthreads();
  // ---- epilogue: out(511) + h_n, c_n
  if (!ish && lane < 16) {
    const int row = wv * 16 + lane;
    float4 o4 = make_float4(hvals[1][0][row], hvals[1][1][row],
                            hvals[1][2][row], hvals[1][3][row]);
    *(float4*)(out + ((size_t)(T_ - 1) * 64 + row) * 1024 + cu * 4) = o4;
  }
  if (ish) {
    out[(size_t)T_ * 65536 + (size_t)eb * 1024 + j] = hval;
    out[(size_t)T_ * 65536 + 65536 + (size_t)eb * 1024 + j] = cst;
  }
}

extern "C" void kernel_launch(void* const* d_in, const int* in_sizes, int n_in,
                              void* d_out, int out_size, void* d_ws, size_t ws_size,
                              hipStream_t stream) {
  (void)in_sizes; (void)n_in;
  const float* X  = (const float*)d_in[0];
  const float* Wi = (const float*)d_in[1];
  const float* Wh = (const float*)d_in[2];
  const float* bi = (const float*)d_in[3];
  const float* bh = (const float*)d_in[4];
  float* out = (float*)d_out;

  char* ws = (char*)d_ws;
  const size_t W_BYTES = (size_t)256 * 64 * 64 * 8 * 2;     // 16,777,216
  const size_t H_BYTES = (size_t)2 * 4 * 32 * 64 * 8 * 2;   //    262,144
  const size_t C_BYTES = 8192;                              // ctrs + 8 flag copies
  const size_t X_BYTES = (size_t)512 * 4 * 32 * 64 * 8 * 2; // 67,108,864

  bf16_8* wfrag = (bf16_8*)ws;
  bf16_8* hfrag = (bf16_8*)(ws + W_BYTES);
  unsigned int* ctr = (unsigned int*)(ws + W_BYTES + H_BYTES);

  bf16_8* xfrag;
  if (ws_size >= W_BYTES + H_BYTES + C_BYTES + X_BYTES) {
    xfrag = (bf16_8*)(ws + W_BYTES + H_BYTES + C_BYTES);
  } else {
    // place x-frags in the tail of d_out; out rows clobber xfrag[t'] only for
    // t' < 2t-514 < t+1 (already consumed, skew<=1); final outputs cover all.
    size_t out_bytes = (size_t)out_size * 4;
    xfrag = (bf16_8*)((char*)d_out + out_bytes - X_BYTES);
  }

  hipMemsetAsync(hfrag, 0, 131072, stream);   // zero h buffer 0 (t=0 reads it)
  hipMemsetAsync(ctr, 0, C_BYTES, stream);    // reset counters + flag copies

  hipLaunchKernelGGL(p1_xfrag, dim3(16384), dim3(256), 0, stream, X, xfrag);
  hipLaunchKernelGGL(p2_wfrag, dim3(4096), dim3(256), 0, stream, Wi, Wh, wfrag);
  hipLaunchKernelGGL(lstm_persist, dim3(256), dim3(512), 0, stream,
                     bi, bh, (const s16_8*)xfrag, (const s16_8*)wfrag,
                     (s16_8*)hfrag, out, ctr);
}